// Round 3
// baseline (872.923 us; speedup 1.0000x reference)
//
#include <hip/hip_runtime.h>

// MessagePassing: B=262144 independent 5-node ring GNN evaluations.
// R3: fix R2's x-staging index bug (store linear, read tid*30+j — R1's proven
// scheme). Weights via wave-uniform literal-index loads -> s_load promotion.
// Wu-fold precomputed into d_ws by a tiny prep kernel (on-the-fly fold was a
// net-zero trade of FMAs for VALU adds). Target: fp32 VALU bound (~35-60 us).

#define NH 18

__device__ __forceinline__ float fast_tanh(float x) {
    // tanh(x) = 1 - 2/(exp(2x)+1). exp2 + rcp, error ~1e-6.
    float t = __builtin_amdgcn_exp2f(x * 2.8853900817779268f); // 2*log2(e)
    float r = __builtin_amdgcn_rcpf(t + 1.0f);
    return __builtin_fmaf(-2.0f, r, 1.0f);
}

__global__ __launch_bounds__(384) void fold_kernel(const float* __restrict__ Wu,
                                                   float* __restrict__ WuH) {
    int i = threadIdx.x;
    if (i < NH * NH) WuH[i] = Wu[NH * NH + i] + Wu[2 * NH * NH + i];
}

template <bool FOLD>
__global__ __launch_bounds__(256) void mp_kernel(
    const float* __restrict__ x,
    const float* __restrict__ Wf, const float* __restrict__ bf,
    const float* __restrict__ Wm, const float* __restrict__ bm,
    const float* __restrict__ Wu, const float* __restrict__ bu,
    const float* __restrict__ Wr, const float* __restrict__ br,
    const float* __restrict__ WuH,   // folded Wu rows 18..35 + 36..53 (if FOLD)
    float* __restrict__ out, int B)
{
    __shared__ float sx[256 * 30];   // x stage for coalescing, 30 KB

    const int tid = threadIdx.x;
    const long long base = (long long)blockIdx.x * (256 * 30);
    const long long xtot = (long long)B * 30;
    #pragma unroll
    for (int i = 0; i < 30; ++i) {
        long long g = base + i * 256 + tid;
        sx[i * 256 + tid] = (g < xtot) ? x[g] : 0.0f;   // linear: sx[m]=x[base+m]
    }
    __syncthreads();

    // ---- Stage 1: h[n][k] = tanh(x[n] @ Wf + bf) ----
    // All weight/bias reads have compile-time-constant indices into const
    // __restrict__ kernel args -> wave-uniform -> s_load (SGPR operands).
    float h[5][NH];
    #pragma unroll
    for (int n = 0; n < 5; ++n) {
        float acc[NH];
        #pragma unroll
        for (int k = 0; k < NH; ++k) acc[k] = bf[k];
        #pragma unroll
        for (int f = 0; f < 6; ++f) {
            float xf = sx[tid * 30 + n * 6 + f];
            #pragma unroll
            for (int k = 0; k < NH; ++k)
                acc[k] = __builtin_fmaf(xf, Wf[f * NH + k], acc[k]);
        }
        #pragma unroll
        for (int k = 0; k < NH; ++k) h[n][k] = fast_tanh(acc[k]);
    }

    // ---- Stage 2/3 interleaved, ring buffer on M ----
    // M[n]  = tanh([h[n], h[(n+1)%5]] @ Wm + bm)
    // U2[n] = tanh([M[n-1], h[n], h[n]] @ Wu + bu); racc += U2[n] . Wr[n]
    float Mprev[NH];
    { // Mprev = M[4] from h[4], h[0]
        float acc[NH];
        #pragma unroll
        for (int k = 0; k < NH; ++k) acc[k] = bm[k];
        #pragma unroll
        for (int j = 0; j < NH; ++j) {
            float a = h[4][j], b = h[0][j];
            #pragma unroll
            for (int k = 0; k < NH; ++k)
                acc[k] = __builtin_fmaf(b, Wm[(NH + j) * NH + k],
                          __builtin_fmaf(a, Wm[j * NH + k], acc[k]));
        }
        #pragma unroll
        for (int k = 0; k < NH; ++k) Mprev[k] = fast_tanh(acc[k]);
    }

    float racc = br[0];
    #pragma unroll
    for (int n = 0; n < 5; ++n) {
        { // U2[n] from Mprev (= M[n-1]) and h[n]
            float acc[NH];
            #pragma unroll
            for (int k = 0; k < NH; ++k) acc[k] = bu[k];
            #pragma unroll
            for (int j = 0; j < NH; ++j) {
                float m = Mprev[j], hv = h[n][j];
                #pragma unroll
                for (int k = 0; k < NH; ++k) {
                    acc[k] = __builtin_fmaf(m, Wu[j * NH + k], acc[k]);
                    if (FOLD) {
                        acc[k] = __builtin_fmaf(hv, WuH[j * NH + k], acc[k]);
                    } else {
                        acc[k] = __builtin_fmaf(hv, Wu[(NH + j) * NH + k], acc[k]);
                        acc[k] = __builtin_fmaf(hv, Wu[(2 * NH + j) * NH + k], acc[k]);
                    }
                }
            }
            #pragma unroll
            for (int k = 0; k < NH; ++k)
                racc = __builtin_fmaf(fast_tanh(acc[k]), Wr[n * NH + k], racc);
        }
        if (n < 4) { // Mprev <- M[n] from h[n], h[n+1]
            float acc[NH];
            #pragma unroll
            for (int k = 0; k < NH; ++k) acc[k] = bm[k];
            #pragma unroll
            for (int j = 0; j < NH; ++j) {
                float a = h[n][j], b = h[n + 1][j];
                #pragma unroll
                for (int k = 0; k < NH; ++k)
                    acc[k] = __builtin_fmaf(b, Wm[(NH + j) * NH + k],
                              __builtin_fmaf(a, Wm[j * NH + k], acc[k]));
            }
            #pragma unroll
            for (int k = 0; k < NH; ++k) Mprev[k] = fast_tanh(acc[k]);
        }
    }

    long long b = (long long)blockIdx.x * 256 + tid;
    if (b < B) out[b] = racc;
}

extern "C" void kernel_launch(void* const* d_in, const int* in_sizes, int n_in,
                              void* d_out, int out_size, void* d_ws, size_t ws_size,
                              hipStream_t stream) {
    const float* x  = (const float*)d_in[0];
    const float* Wf = (const float*)d_in[1];
    const float* bf = (const float*)d_in[2];
    const float* Wm = (const float*)d_in[3];
    const float* bm = (const float*)d_in[4];
    const float* Wu = (const float*)d_in[5];
    const float* bu = (const float*)d_in[6];
    const float* Wr = (const float*)d_in[7];
    const float* br = (const float*)d_in[8];
    float* out = (float*)d_out;

    const int B = in_sizes[0] / 30;          // [B,5,6]
    const int grid = (B + 255) / 256;

    if (ws_size >= NH * NH * sizeof(float)) {
        float* WuH = (float*)d_ws;
        fold_kernel<<<1, 384, 0, stream>>>(Wu, WuH);
        mp_kernel<true><<<grid, 256, 0, stream>>>(x, Wf, bf, Wm, bm, Wu, bu,
                                                  Wr, br, WuH, out, B);
    } else {
        mp_kernel<false><<<grid, 256, 0, stream>>>(x, Wf, bf, Wm, bm, Wu, bu,
                                                   Wr, br, nullptr, out, B);
    }
}

// Round 4
// 226.518 us; speedup vs baseline: 3.8537x; 3.8537x over previous
//
#include <hip/hip_runtime.h>
#include <stdint.h>

// MessagePassing R4: stages 2+3 on f16 MFMA (16x16x32), stage1 fp32 VALU.
// R1 was LDS-broadcast-operand-bound (~17% FMA util ceiling); MFMA's HW
// operand sharing breaks that wall. B-fragments pre-baked lane-exact into ws
// by prep kernel. h/M staged in LDS in concat-friendly f16 layouts.

#define NH 18
#define EHDW 66          // bufh element stride, dwords (132 f16: 6 node slots x18 + pad)
#define EMDW 87          // bufM element stride, dwords (5 row slots x 17dw)
#define BUFM_DW 8448     // 128*EHDW
#define RED_DW 19584     // BUFM_DW + 128*EMDW
#define WRL_DW 20224     // RED_DW + 640
#define LDS_DW 20384     // total dwords = 81536 B (2 blocks/CU)

typedef _Float16 half8 __attribute__((ext_vector_type(8)));
typedef float float4v __attribute__((ext_vector_type(4)));
union AB { uint32_t u[4]; half8 v; };

__device__ __forceinline__ float fast_tanh(float x) {
    float t = __builtin_amdgcn_exp2f(x * 2.8853900817779268f);
    float r = __builtin_amdgcn_rcpf(t + 1.0f);
    return __builtin_fmaf(-2.0f, r, 1.0f);
}
__device__ __forceinline__ uint32_t pkh(float a, float b) {
    union { _Float16 h[2]; uint32_t u; } z;
    z.h[0] = (_Float16)a; z.h[1] = (_Float16)b; return z.u;
}

// ---- prep: bake B-fragments (lane-exact) + padded biases/Wr into ws ----
// frag f = stage*4 + ct*2 + ks; value[lane][j] = B[k=ks*32+(lane>>4)*8+j][n=ct*16+(lane&15)]
// stage0: Wm[36][18]; stage1: Wu rows 0..17 | fold(Wu[18..35]+Wu[36..53]); 0-padded.
__global__ __launch_bounds__(256) void prep_kernel(
    const float* __restrict__ Wm, const float* __restrict__ Wu,
    const float* __restrict__ bm, const float* __restrict__ bu,
    const float* __restrict__ Wr, void* __restrict__ ws)
{
    _Float16* wsh = (_Float16*)ws;
    float* wsf = (float*)ws;
    int tid = threadIdx.x;
    for (int i = tid; i < 512; i += 256) {
        int f = i >> 6, lane = i & 63;
        int s = f >> 2, ct = (f >> 1) & 1, ks = f & 1;
        int n = ct * 16 + (lane & 15);
        int kb = ks * 32 + (lane >> 4) * 8;
        for (int j = 0; j < 8; ++j) {
            int k = kb + j;
            float v = 0.0f;
            if (k < 36 && n < NH) {
                if (s == 0) v = Wm[k * NH + n];
                else v = (k < NH) ? Wu[k * NH + n]
                                  : (Wu[k * NH + n] + Wu[(k + NH) * NH + n]);
            }
            wsh[f * 512 + lane * 8 + j] = (_Float16)v;
        }
    }
    if (tid < 32) wsf[2048 + tid] = (tid < NH) ? bm[tid] : 0.0f;
    else if (tid < 64) { int c = tid - 32; wsf[2080 + c] = (c < NH) ? bu[c] : 0.0f; }
    for (int i = tid; i < 160; i += 256) {
        int n = i >> 5, c = i & 31;
        wsf[2112 + i] = (c < NH) ? Wr[n * NH + c] : 0.0f;
    }
}

__global__ __launch_bounds__(256) void mp_mfma(
    const float* __restrict__ x,
    const float* __restrict__ Wf, const float* __restrict__ bf,
    const float* __restrict__ br,
    const float* __restrict__ ws, float* __restrict__ out, int B)
{
    __shared__ uint32_t lds32[LDS_DW];
    _Float16* lds16 = (_Float16*)lds32;
    float* ldsf = (float*)lds32;
    float* red = ldsf + RED_DW;     // rowsums [640] (stage3); [0..125] = sWf in stage1
    float* WrL = ldsf + WRL_DW;     // Wr padded [5][32]
    float* sWf = red;               // Wf[108] + bf[18], stage1 only
    float* sx  = ldsf;              // x stage (15 KB), overlays bufh pre-stage1

    const int tid = threadIdx.x;
    const int lane = tid & 63;
    const int w = tid >> 6;
    const int l15 = lane & 15;
    const int q = lane >> 4;

    // B-fragments: 8 x 16B per lane (coalesced, L2-resident)
    AB Bf[8];
    #pragma unroll
    for (int f = 0; f < 8; ++f) {
        const uint32_t* p = (const uint32_t*)ws + (f * 64 + lane) * 4;
        Bf[f].u[0] = p[0]; Bf[f].u[1] = p[1]; Bf[f].u[2] = p[2]; Bf[f].u[3] = p[3];
    }
    const float bm0 = ws[2048 + l15], bm1 = ws[2048 + 16 + l15];
    const float bu0 = ws[2080 + l15], bu1 = ws[2080 + 16 + l15];

    if (tid < 126) sWf[tid] = (tid < 108) ? Wf[tid] : bf[tid - 108];
    for (int i = tid; i < 160; i += 256) WrL[i] = ws[2112 + i];

    const long long xbase = (long long)blockIdx.x * (128 * 30);
    const long long xtot = (long long)B * 30;
    #pragma unroll
    for (int i = 0; i < 15; ++i) {
        long long g = xbase + i * 256 + tid;
        sx[i * 256 + tid] = (g < xtot) ? x[g] : 0.0f;
    }
    __syncthreads();

    float xv[30];
    if (tid < 128) {
        #pragma unroll
        for (int i = 0; i < 30; ++i) xv[i] = sx[tid * 30 + i];
    }
    __syncthreads();   // x region is overwritten by h image below

    // ---- Stage 1 (fp32 VALU): h = tanh(x@Wf+bf); write f16 images ----
    if (tid < 128) {
        const int e = tid;
        float h[5][NH];
        #pragma unroll
        for (int n = 0; n < 5; ++n) {
            float acc[NH];
            #pragma unroll
            for (int k = 0; k < NH; ++k) acc[k] = sWf[108 + k];
            #pragma unroll
            for (int f = 0; f < 6; ++f) {
                float xf = xv[n * 6 + f];
                #pragma unroll
                for (int k = 0; k < NH; ++k)
                    acc[k] = __builtin_fmaf(xf, sWf[f * NH + k], acc[k]);
            }
            #pragma unroll
            for (int k = 0; k < NH; ++k) h[n][k] = fast_tanh(acc[k]);
        }
        // bufh: 6 node slots (slot5 = dup of node0) -> [h_n|h_{n+1}] contiguous
        #pragma unroll
        for (int s = 0; s < 6; ++s) {
            const float* hv = h[s == 5 ? 0 : s];
            #pragma unroll
            for (int d = 0; d < 9; ++d)
                lds32[e * EHDW + s * 9 + d] = pkh(hv[2 * d], hv[2 * d + 1]);
        }
        // bufM row n tail: h[n][0..5] at dwords 9..11 (stage3 k=18..23)
        #pragma unroll
        for (int n = 0; n < 5; ++n) {
            #pragma unroll
            for (int t = 0; t < 3; ++t)
                lds32[BUFM_DW + e * EMDW + n * 17 + 9 + t] =
                    pkh(h[n][2 * t], h[n][2 * t + 1]);
        }
    }
    __syncthreads();

    // ---- Stage 2 (MFMA): M[n] = tanh([h_n|h_{n+1}]@Wm + bm) ----
    // A row m=(e,n): 36 f16 contiguous at bufh[e*132 + n*18]. M[n] stored to
    // bufM slot (n+1)%5 so stage3 row n holds M[n-1].
    #pragma unroll 1
    for (int i = 0; i < 10; ++i) {
        const int rt = w + 4 * i;
        const int m = rt * 16 + l15;
        const int e = (int)(((unsigned)m * 52429u) >> 18);
        const int n = m - e * 5;
        const int bh = e * EHDW + n * 9;
        AB a0, a1;
        #pragma unroll
        for (int t = 0; t < 4; ++t) a0.u[t] = lds32[bh + q * 4 + t];
        a1.u[0] = a1.u[1] = a1.u[2] = a1.u[3] = 0;
        if (q == 0) { a1.u[0] = lds32[bh + 16]; a1.u[1] = lds32[bh + 17]; }

        int e2[4], sl[4];
        #pragma unroll
        for (int r = 0; r < 4; ++r) {
            int mr = rt * 16 + q * 4 + r;
            e2[r] = (int)(((unsigned)mr * 52429u) >> 18);
            int n2 = mr - e2[r] * 5;
            sl[r] = (n2 == 4) ? 0 : (n2 + 1);
        }
        #pragma unroll
        for (int ct = 0; ct < 2; ++ct) {
            float4v C = {0.f, 0.f, 0.f, 0.f};
            C = __builtin_amdgcn_mfma_f32_16x16x32_f16(a0.v, Bf[ct * 2 + 0].v, C, 0, 0, 0);
            C = __builtin_amdgcn_mfma_f32_16x16x32_f16(a1.v, Bf[ct * 2 + 1].v, C, 0, 0, 0);
            const int col = ct * 16 + l15;
            const float bmv = ct ? bm1 : bm0;
            if (col < NH) {
                #pragma unroll
                for (int r = 0; r < 4; ++r) {
                    float mv = fast_tanh(C[r] + bmv);
                    lds16[(BUFM_DW + e2[r] * EMDW + sl[r] * 17) * 2 + col] = (_Float16)mv;
                }
            }
        }
    }
    __syncthreads();

    // ---- Stage 3 (MFMA): U2 = tanh([M_{n-1}|h_n]@W3 + bu); readout ----
    float wrv[2][5];
    #pragma unroll
    for (int n = 0; n < 5; ++n) {
        wrv[0][n] = WrL[n * 32 + l15];
        wrv[1][n] = WrL[n * 32 + 16 + l15];
    }
    const float brv = br[0];

    #pragma unroll 1
    for (int i = 0; i < 10; ++i) {
        const int rt = w + 4 * i;
        const int m = rt * 16 + l15;
        const int e = (int)(((unsigned)m * 52429u) >> 18);
        const int n = m - e * 5;
        const int bh = e * EHDW + n * 9;
        const int bM = BUFM_DW + e * EMDW + n * 17;
        // q0,q1: M[0..15]; q2: [M16,M17,h0..5] (tail trick); q3: h[6..13] from bufh
        const int src = (q < 3) ? (bM + q * 4) : (bh + 3);
        AB a0, a1;
        #pragma unroll
        for (int t = 0; t < 4; ++t) a0.u[t] = lds32[src + t];
        a1.u[0] = a1.u[1] = a1.u[2] = a1.u[3] = 0;
        if (q == 0) { a1.u[0] = lds32[bh + 7]; a1.u[1] = lds32[bh + 8]; } // h[14..17]

        int n2[4];
        #pragma unroll
        for (int r = 0; r < 4; ++r) {
            int mr = rt * 16 + q * 4 + r;
            int er = (int)(((unsigned)mr * 52429u) >> 18);
            n2[r] = mr - er * 5;
        }
        float pr[4] = {0.f, 0.f, 0.f, 0.f};
        #pragma unroll
        for (int ct = 0; ct < 2; ++ct) {
            float4v C = {0.f, 0.f, 0.f, 0.f};
            C = __builtin_amdgcn_mfma_f32_16x16x32_f16(a0.v, Bf[4 + ct * 2 + 0].v, C, 0, 0, 0);
            C = __builtin_amdgcn_mfma_f32_16x16x32_f16(a1.v, Bf[4 + ct * 2 + 1].v, C, 0, 0, 0);
            const float buv = ct ? bu1 : bu0;
            #pragma unroll
            for (int r = 0; r < 4; ++r) {
                float u = fast_tanh(C[r] + buv);   // cols>=18: C=0,wr=0 -> inert
                int nn = n2[r];
                float wr = (nn == 0) ? wrv[ct][0] :
                           (nn == 1) ? wrv[ct][1] :
                           (nn == 2) ? wrv[ct][2] :
                           (nn == 3) ? wrv[ct][3] : wrv[ct][4];
                pr[r] = __builtin_fmaf(u, wr, pr[r]);
            }
        }
        #pragma unroll
        for (int r = 0; r < 4; ++r) {           // reduce over 16 cols-lanes
            float s = pr[r];
            s += __shfl_xor(s, 1, 16);
            s += __shfl_xor(s, 2, 16);
            s += __shfl_xor(s, 4, 16);
            s += __shfl_xor(s, 8, 16);
            if (l15 == r) red[rt * 16 + q * 4 + r] = s;
        }
    }
    __syncthreads();

    if (tid < 128) {
        long long b = (long long)blockIdx.x * 128 + tid;
        float s = brv;
        #pragma unroll
        for (int n = 0; n < 5; ++n) s += red[tid * 5 + n];
        if (b < B) out[b] = s;
    }
}

// ---- Fallback (proven R1, 160 us): used only if ws too small ----
__global__ __launch_bounds__(256) void mp_fallback(
    const float* __restrict__ x,
    const float* __restrict__ Wf, const float* __restrict__ bf,
    const float* __restrict__ Wm, const float* __restrict__ bm,
    const float* __restrict__ Wu, const float* __restrict__ bu,
    const float* __restrict__ Wr, const float* __restrict__ br,
    float* __restrict__ out, int B)
{
    __shared__ float sWf[6 * NH]; __shared__ float sbf[NH];
    __shared__ float sWm[36 * NH]; __shared__ float sbm[NH];
    __shared__ float sWuM[NH * NH]; __shared__ float sWuH[NH * NH];
    __shared__ float sbu[NH]; __shared__ float sWr[5 * NH];
    __shared__ float sx[256 * 30];
    const int tid = threadIdx.x;
    for (int i = tid; i < 6 * NH; i += 256) sWf[i] = Wf[i];
    for (int i = tid; i < 36 * NH; i += 256) sWm[i] = Wm[i];
    for (int i = tid; i < NH * NH; i += 256) {
        sWuM[i] = Wu[i];
        sWuH[i] = Wu[NH * NH + i] + Wu[2 * NH * NH + i];
    }
    for (int i = tid; i < 5 * NH; i += 256) sWr[i] = Wr[i];
    if (tid < NH) { sbf[tid] = bf[tid]; sbm[tid] = bm[tid]; sbu[tid] = bu[tid]; }
    const long long base = (long long)blockIdx.x * (256 * 30);
    const long long xtot = (long long)B * 30;
    for (int i = tid; i < 256 * 30; i += 256) {
        long long g = base + i;
        sx[i] = (g < xtot) ? x[g] : 0.0f;
    }
    __syncthreads();
    float h[5][NH];
    #pragma unroll
    for (int n = 0; n < 5; ++n) {
        float acc[NH];
        #pragma unroll
        for (int k = 0; k < NH; ++k) acc[k] = sbf[k];
        #pragma unroll
        for (int f = 0; f < 6; ++f) {
            float xf = sx[tid * 30 + n * 6 + f];
            #pragma unroll
            for (int k = 0; k < NH; ++k)
                acc[k] = __builtin_fmaf(xf, sWf[f * NH + k], acc[k]);
        }
        #pragma unroll
        for (int k = 0; k < NH; ++k) h[n][k] = fast_tanh(acc[k]);
    }
    float Mprev[NH];
    {
        float acc[NH];
        #pragma unroll
        for (int k = 0; k < NH; ++k) acc[k] = sbm[k];
        #pragma unroll
        for (int j = 0; j < NH; ++j) {
            float a = h[4][j], b = h[0][j];
            #pragma unroll
            for (int k = 0; k < NH; ++k)
                acc[k] = __builtin_fmaf(b, sWm[(NH + j) * NH + k],
                          __builtin_fmaf(a, sWm[j * NH + k], acc[k]));
        }
        #pragma unroll
        for (int k = 0; k < NH; ++k) Mprev[k] = fast_tanh(acc[k]);
    }
    float racc = br[0];
    #pragma unroll
    for (int n = 0; n < 5; ++n) {
        {
            float acc[NH];
            #pragma unroll
            for (int k = 0; k < NH; ++k) acc[k] = sbu[k];
            #pragma unroll
            for (int j = 0; j < NH; ++j) {
                float mval = Mprev[j], hv = h[n][j];
                #pragma unroll
                for (int k = 0; k < NH; ++k)
                    acc[k] = __builtin_fmaf(hv, sWuH[j * NH + k],
                              __builtin_fmaf(mval, sWuM[j * NH + k], acc[k]));
            }
            #pragma unroll
            for (int k = 0; k < NH; ++k)
                racc = __builtin_fmaf(fast_tanh(acc[k]), sWr[n * NH + k], racc);
        }
        if (n < 4) {
            float acc[NH];
            #pragma unroll
            for (int k = 0; k < NH; ++k) acc[k] = sbm[k];
            #pragma unroll
            for (int j = 0; j < NH; ++j) {
                float a = h[n][j], b = h[n + 1][j];
                #pragma unroll
                for (int k = 0; k < NH; ++k)
                    acc[k] = __builtin_fmaf(b, sWm[(NH + j) * NH + k],
                              __builtin_fmaf(a, sWm[j * NH + k], acc[k]));
            }
            #pragma unroll
            for (int k = 0; k < NH; ++k) Mprev[k] = fast_tanh(acc[k]);
        }
    }
    long long b = (long long)blockIdx.x * 256 + tid;
    if (b < B) out[b] = racc;
}

extern "C" void kernel_launch(void* const* d_in, const int* in_sizes, int n_in,
                              void* d_out, int out_size, void* d_ws, size_t ws_size,
                              hipStream_t stream) {
    const float* x  = (const float*)d_in[0];
    const float* Wf = (const float*)d_in[1];
    const float* bf = (const float*)d_in[2];
    const float* Wm = (const float*)d_in[3];
    const float* bm = (const float*)d_in[4];
    const float* Wu = (const float*)d_in[5];
    const float* bu = (const float*)d_in[6];
    const float* Wr = (const float*)d_in[7];
    const float* br = (const float*)d_in[8];
    float* out = (float*)d_out;
    const int B = in_sizes[0] / 30;

    if (ws_size >= 9088) {
        prep_kernel<<<1, 256, 0, stream>>>(Wm, Wu, bm, bu, Wr, d_ws);
        const int grid = (B + 127) / 128;
        mp_mfma<<<grid, 256, 0, stream>>>(x, Wf, bf, br, (const float*)d_ws, out, B);
    } else {
        const int grid = (B + 255) / 256;
        mp_fallback<<<grid, 256, 0, stream>>>(x, Wf, bf, Wm, bm, Wu, bu, Wr, br, out, B);
    }
}

// Round 5
// 139.219 us; speedup vs baseline: 6.2702x; 1.6271x over previous
//
#include <hip/hip_runtime.h>
#include <stdint.h>

// MessagePassing R5: all three stages on f16 MFMA (16x16x32), edge-batched row
// mapping (rows = elements; n,b loops compile-time -> no div/mod-5), LDS cut
// to 50.2 KB -> 3 blocks/CU, full unrolls for ILP. R4 was latency-bound
// (2 waves/SIMD, unroll-1, half-idle stage1): MfmaUtil 2.7 / VALU 37 / HBM 1.4.

#define NH 18
#define EL 128              // elements per block
#define SH 47               // bufh element stride, dwords (5 slots x 9dw + 2 pad, odd)
#define SM 51               // bufM element stride, dwords (5 slots x 10dw + 1 pad, odd)
#define BUFM_BASE 6016      // 128*SH
#define LDS_DW 12544        // BUFM_BASE + 128*SM = 50176 B -> 3 blocks/CU
#define X16_BASE BUFM_BASE  // x (f16 A-layout) overlays bufM; dead before stage2
#define WS_BYTES 11264      // 2816 dwords

typedef _Float16 half8 __attribute__((ext_vector_type(8)));
typedef float float4v __attribute__((ext_vector_type(4)));
union AB { uint32_t u[4]; half8 v; };

__device__ __forceinline__ float fast_tanh(float x) {
    float t = __builtin_amdgcn_exp2f(x * 2.8853900817779268f);
    float r = __builtin_amdgcn_rcpf(t + 1.0f);
    return __builtin_fmaf(-2.0f, r, 1.0f);
}
__device__ __forceinline__ uint32_t pkh(float a, float b) {
    union { _Float16 h[2]; uint32_t u; } z;
    z.h[0] = (_Float16)a; z.h[1] = (_Float16)b; return z.u;
}

// ---- prep: bake B-fragments + padded biases/Wr into ws ----
// ws dwords: frag f at f*256 + lane*4 (f16x8/lane).
//   f=0,1: Wf (ct=f, ks=0, k<6); f=2..5: Wm (ct=(f-2)>>1, ks=(f-2)&1, k<36);
//   f=6..9: Wu folded rows 18..35 + 36..53 (ct=(f-6)>>1, ks=(f-6)&1, k<36).
// f32: bf[32]@2560, bm[32]@2592, bu[32]@2624, Wr[5][32]@2656 (end 2816).
__global__ __launch_bounds__(640) void prep_kernel(
    const float* __restrict__ Wf, const float* __restrict__ bf,
    const float* __restrict__ Wm, const float* __restrict__ bm,
    const float* __restrict__ Wu, const float* __restrict__ bu,
    const float* __restrict__ Wr, void* __restrict__ ws)
{
    _Float16* wsh = (_Float16*)ws;
    float* wsf = (float*)ws;
    int tid = threadIdx.x;
    for (int i = tid; i < 640; i += 640) {
        int f = i >> 6, lane = i & 63;
        int q = lane >> 4, l15 = lane & 15;
        int ct, ks, which;
        if (f < 2)      { which = 0; ct = f;            ks = 0; }
        else if (f < 6) { which = 1; ct = (f - 2) >> 1; ks = (f - 2) & 1; }
        else            { which = 2; ct = (f - 6) >> 1; ks = (f - 6) & 1; }
        int col = ct * 16 + l15;
        for (int j = 0; j < 8; ++j) {
            int k = ks * 32 + q * 8 + j;
            float v = 0.0f;
            if (col < NH) {
                if (which == 0)      { if (k < 6)  v = Wf[k * NH + col]; }
                else if (which == 1) { if (k < 36) v = Wm[k * NH + col]; }
                else                 { if (k < 36) v = (k < NH) ? Wu[k * NH + col]
                                        : (Wu[k * NH + col] + Wu[(k + NH) * NH + col]); }
            }
            wsh[(f * 256 + lane * 4 + (j >> 1)) * 2 + (j & 1)] = (_Float16)v;
        }
    }
    if (tid < 32)       wsf[2560 + tid] = (tid < NH) ? bf[tid] : 0.0f;
    else if (tid < 64)  { int c = tid - 32; wsf[2592 + c] = (c < NH) ? bm[c] : 0.0f; }
    else if (tid < 96)  { int c = tid - 64; wsf[2624 + c] = (c < NH) ? bu[c] : 0.0f; }
    for (int i = tid; i < 160; i += 640) {
        int n = i >> 5, c = i & 31;
        wsf[2656 + i] = (c < NH) ? Wr[n * NH + c] : 0.0f;
    }
}

__global__ __launch_bounds__(256, 3) void mp_mfma(
    const float* __restrict__ x, const float* __restrict__ br,
    const uint32_t* __restrict__ ws, float* __restrict__ out, int B)
{
    __shared__ uint32_t lds32[LDS_DW];
    _Float16* lds16 = (_Float16*)lds32;

    const int tid = threadIdx.x;
    const int lane = tid & 63;
    const int w = tid >> 6;
    const int l15 = lane & 15;
    const int q = lane >> 4;
    const float* wsf = (const float*)ws;

    // B-fragments (coalesced 16B/lane, L2-resident)
    AB Ff[2], Fm[2][2], Fu[2][2];
    #pragma unroll
    for (int ct = 0; ct < 2; ++ct) {
        const uint32_t* p = ws + (ct * 256 + lane * 4);
        #pragma unroll
        for (int t = 0; t < 4; ++t) Ff[ct].u[t] = p[t];
        #pragma unroll
        for (int ks = 0; ks < 2; ++ks) {
            const uint32_t* pm = ws + ((2 + ct * 2 + ks) * 256 + lane * 4);
            const uint32_t* pu = ws + ((6 + ct * 2 + ks) * 256 + lane * 4);
            #pragma unroll
            for (int t = 0; t < 4; ++t) { Fm[ct][ks].u[t] = pm[t]; Fu[ct][ks].u[t] = pu[t]; }
        }
    }
    float bfv[2], bmv[2], buv[2], wrv[2][5];
    #pragma unroll
    for (int ct = 0; ct < 2; ++ct) {
        int col = ct * 16 + l15;
        bfv[ct] = wsf[2560 + col];
        bmv[ct] = wsf[2592 + col];
        buv[ct] = wsf[2624 + col];
        #pragma unroll
        for (int n = 0; n < 5; ++n) wrv[ct][n] = wsf[2656 + n * 32 + col];
    }
    const float brv = br[0];

    // ---- x stage: f32 pairs -> f16 A-layout x16[n][e][3dw] at X16_BASE ----
    const long long pbase = (long long)blockIdx.x * (EL * 15);
    const long long ptot = (long long)B * 15;
    #pragma unroll
    for (int it = 0; it < 8; ++it) {
        int j = it * 256 + tid;
        if (j < EL * 15) {
            long long gp = pbase + j;
            float2 xv = make_float2(0.f, 0.f);
            if (gp < ptot) xv = ((const float2*)x)[gp];
            unsigned e = (unsigned)j / 15u;
            unsigned rem = (unsigned)j - e * 15u;
            unsigned n = rem / 3u;
            unsigned d = rem - n * 3u;
            lds32[X16_BASE + n * (EL * 3) + e * 3 + d] = pkh(xv.x, xv.y);
        }
    }
    __syncthreads();

    // ---- Stage 1 (MFMA): h[e][n] = tanh(x@Wf+bf); bufh[e*SH + n*9] f16 ----
    #pragma unroll
    for (int n = 0; n < 5; ++n) {
        #pragma unroll
        for (int b = 0; b < 2; ++b) {
            const int ebase = (w + 4 * b) * 16;
            const int e = ebase + l15;
            AB a; a.u[0] = a.u[1] = a.u[2] = a.u[3] = 0;
            if (q == 0) {
                int o = X16_BASE + n * (EL * 3) + e * 3;
                a.u[0] = lds32[o]; a.u[1] = lds32[o + 1]; a.u[2] = lds32[o + 2];
            }
            #pragma unroll
            for (int ct = 0; ct < 2; ++ct) {
                float4v C = {0.f, 0.f, 0.f, 0.f};
                C = __builtin_amdgcn_mfma_f32_16x16x32_f16(a.v, Ff[ct].v, C, 0, 0, 0);
                #pragma unroll
                for (int r = 0; r < 4; ++r) {
                    if (ct == 0 || l15 < 2) {
                        int e2 = ebase + q * 4 + r;
                        float hv = fast_tanh(C[r] + bfv[ct]);
                        lds16[(e2 * SH + n * 9) * 2 + ct * 16 + l15] = (_Float16)hv;
                    }
                }
            }
        }
    }
    __syncthreads();

    // ---- Stage 2 (MFMA): M[n] = tanh([h_n|h_{n+1}]@Wm+bm) -> bufM slot n+1 ----
    #pragma unroll
    for (int n = 0; n < 5; ++n) {
        const int n2 = (n == 4) ? 0 : n + 1;
        #pragma unroll
        for (int b = 0; b < 2; ++b) {
            const int ebase = (w + 4 * b) * 16;
            const int e = ebase + l15;
            const int o0 = e * SH + n * 9, o2 = e * SH + n2 * 9;
            AB a0, a1;
            if (q == 2) {   // k16..23: h_n[16,17] + h_{n+1}[0..5]
                a0.u[0] = lds32[o0 + 8];
                a0.u[1] = lds32[o2]; a0.u[2] = lds32[o2 + 1]; a0.u[3] = lds32[o2 + 2];
            } else {
                int bs = (q == 0) ? o0 : (q == 1) ? (o0 + 4) : (o2 + 3);
                #pragma unroll
                for (int t = 0; t < 4; ++t) a0.u[t] = lds32[bs + t];
            }
            a1.u[0] = a1.u[1] = a1.u[2] = a1.u[3] = 0;
            if (q == 0) { a1.u[0] = lds32[o2 + 7]; a1.u[1] = lds32[o2 + 8]; } // k32..35
            #pragma unroll
            for (int ct = 0; ct < 2; ++ct) {
                float4v C = {0.f, 0.f, 0.f, 0.f};
                C = __builtin_amdgcn_mfma_f32_16x16x32_f16(a0.v, Fm[ct][0].v, C, 0, 0, 0);
                C = __builtin_amdgcn_mfma_f32_16x16x32_f16(a1.v, Fm[ct][1].v, C, 0, 0, 0);
                #pragma unroll
                for (int r = 0; r < 4; ++r) {
                    if (ct == 0 || l15 < 2) {
                        int e2 = ebase + q * 4 + r;
                        float mv = fast_tanh(C[r] + bmv[ct]);
                        lds16[(BUFM_BASE + e2 * SM + n2 * 10) * 2 + ct * 16 + l15] = (_Float16)mv;
                    }
                }
            }
        }
    }
    __syncthreads();

    // ---- Stage 3 (MFMA): U2 = tanh([M_{n-1}|h_n]@W3+bu); racc per element ----
    float pr[2][4];
    #pragma unroll
    for (int b = 0; b < 2; ++b)
        #pragma unroll
        for (int r = 0; r < 4; ++r) pr[b][r] = 0.0f;

    #pragma unroll
    for (int n = 0; n < 5; ++n) {
        #pragma unroll
        for (int b = 0; b < 2; ++b) {
            const int ebase = (w + 4 * b) * 16;
            const int e = ebase + l15;
            const int oh = e * SH + n * 9;
            const int oM = BUFM_BASE + e * SM + n * 10;   // slot n holds M_{n-1}
            AB a0, a1;
            if (q == 2) {   // k16..23: M[16,17] + h_n[0..5]
                a0.u[0] = lds32[oM + 8];
                a0.u[1] = lds32[oh]; a0.u[2] = lds32[oh + 1]; a0.u[3] = lds32[oh + 2];
            } else {
                int bs = (q == 0) ? oM : (q == 1) ? (oM + 4) : (oh + 3);
                #pragma unroll
                for (int t = 0; t < 4; ++t) a0.u[t] = lds32[bs + t];
            }
            a1.u[0] = a1.u[1] = a1.u[2] = a1.u[3] = 0;
            if (q == 0) { a1.u[0] = lds32[oh + 7]; a1.u[1] = lds32[oh + 8]; } // h[14..17]
            #pragma unroll
            for (int ct = 0; ct < 2; ++ct) {
                float4v C = {0.f, 0.f, 0.f, 0.f};
                C = __builtin_amdgcn_mfma_f32_16x16x32_f16(a0.v, Fu[ct][0].v, C, 0, 0, 0);
                C = __builtin_amdgcn_mfma_f32_16x16x32_f16(a1.v, Fu[ct][1].v, C, 0, 0, 0);
                #pragma unroll
                for (int r = 0; r < 4; ++r) {
                    float u = fast_tanh(C[r] + buv[ct]);  // pad cols: C=0,bu=0 -> 0*0
                    pr[b][r] = __builtin_fmaf(u, wrv[ct][n], pr[b][r]);
                }
            }
        }
    }

    // ---- readout: reduce 16 col-lanes, store ----
    #pragma unroll
    for (int b = 0; b < 2; ++b) {
        #pragma unroll
        for (int r = 0; r < 4; ++r) {
            float s = pr[b][r];
            s += __shfl_xor(s, 1, 16);
            s += __shfl_xor(s, 2, 16);
            s += __shfl_xor(s, 4, 16);
            s += __shfl_xor(s, 8, 16);
            if (l15 == r) {
                long long idx = (long long)blockIdx.x * EL + (w + 4 * b) * 16 + q * 4 + r;
                if (idx < B) out[idx] = s + brv;
            }
        }
    }
}

// ---- Fallback (proven R1, 160 us): used only if ws too small ----
__global__ __launch_bounds__(256) void mp_fallback(
    const float* __restrict__ x,
    const float* __restrict__ Wf, const float* __restrict__ bf,
    const float* __restrict__ Wm, const float* __restrict__ bm,
    const float* __restrict__ Wu, const float* __restrict__ bu,
    const float* __restrict__ Wr, const float* __restrict__ br,
    float* __restrict__ out, int B)
{
    __shared__ float sWf[6 * NH]; __shared__ float sbf[NH];
    __shared__ float sWm[36 * NH]; __shared__ float sbm[NH];
    __shared__ float sWuM[NH * NH]; __shared__ float sWuH[NH * NH];
    __shared__ float sbu[NH]; __shared__ float sWr[5 * NH];
    __shared__ float sx[256 * 30];
    const int tid = threadIdx.x;
    for (int i = tid; i < 6 * NH; i += 256) sWf[i] = Wf[i];
    for (int i = tid; i < 36 * NH; i += 256) sWm[i] = Wm[i];
    for (int i = tid; i < NH * NH; i += 256) {
        sWuM[i] = Wu[i];
        sWuH[i] = Wu[NH * NH + i] + Wu[2 * NH * NH + i];
    }
    for (int i = tid; i < 5 * NH; i += 256) sWr[i] = Wr[i];
    if (tid < NH) { sbf[tid] = bf[tid]; sbm[tid] = bm[tid]; sbu[tid] = bu[tid]; }
    const long long base = (long long)blockIdx.x * (256 * 30);
    const long long xtot = (long long)B * 30;
    for (int i = tid; i < 256 * 30; i += 256) {
        long long g = base + i;
        sx[i] = (g < xtot) ? x[g] : 0.0f;
    }
    __syncthreads();
    float h[5][NH];
    #pragma unroll
    for (int n = 0; n < 5; ++n) {
        float acc[NH];
        #pragma unroll
        for (int k = 0; k < NH; ++k) acc[k] = sbf[k];
        #pragma unroll
        for (int f = 0; f < 6; ++f) {
            float xf = sx[tid * 30 + n * 6 + f];
            #pragma unroll
            for (int k = 0; k < NH; ++k)
                acc[k] = __builtin_fmaf(xf, sWf[f * NH + k], acc[k]);
        }
        #pragma unroll
        for (int k = 0; k < NH; ++k) h[n][k] = fast_tanh(acc[k]);
    }
    float Mprev[NH];
    {
        float acc[NH];
        #pragma unroll
        for (int k = 0; k < NH; ++k) acc[k] = sbm[k];
        #pragma unroll
        for (int j = 0; j < NH; ++j) {
            float a = h[4][j], b = h[0][j];
            #pragma unroll
            for (int k = 0; k < NH; ++k)
                acc[k] = __builtin_fmaf(b, sWm[(NH + j) * NH + k],
                          __builtin_fmaf(a, sWm[j * NH + k], acc[k]));
        }
        #pragma unroll
        for (int k = 0; k < NH; ++k) Mprev[k] = fast_tanh(acc[k]);
    }
    float racc = br[0];
    #pragma unroll
    for (int n = 0; n < 5; ++n) {
        {
            float acc[NH];
            #pragma unroll
            for (int k = 0; k < NH; ++k) acc[k] = sbu[k];
            #pragma unroll
            for (int j = 0; j < NH; ++j) {
                float mval = Mprev[j], hv = h[n][j];
                #pragma unroll
                for (int k = 0; k < NH; ++k)
                    acc[k] = __builtin_fmaf(hv, sWuH[j * NH + k],
                              __builtin_fmaf(mval, sWuM[j * NH + k], acc[k]));
            }
            #pragma unroll
            for (int k = 0; k < NH; ++k)
                racc = __builtin_fmaf(fast_tanh(acc[k]), sWr[n * NH + k], racc);
        }
        if (n < 4) {
            float acc[NH];
            #pragma unroll
            for (int k = 0; k < NH; ++k) acc[k] = sbm[k];
            #pragma unroll
            for (int j = 0; j < NH; ++j) {
                float a = h[n][j], b = h[n + 1][j];
                #pragma unroll
                for (int k = 0; k < NH; ++k)
                    acc[k] = __builtin_fmaf(b, sWm[(NH + j) * NH + k],
                              __builtin_fmaf(a, sWm[j * NH + k], acc[k]));
            }
            #pragma unroll
            for (int k = 0; k < NH; ++k) Mprev[k] = fast_tanh(acc[k]);
        }
    }
    long long b = (long long)blockIdx.x * 256 + tid;
    if (b < B) out[b] = racc;
}

extern "C" void kernel_launch(void* const* d_in, const int* in_sizes, int n_in,
                              void* d_out, int out_size, void* d_ws, size_t ws_size,
                              hipStream_t stream) {
    const float* x  = (const float*)d_in[0];
    const float* Wf = (const float*)d_in[1];
    const float* bf = (const float*)d_in[2];
    const float* Wm = (const float*)d_in[3];
    const float* bm = (const float*)d_in[4];
    const float* Wu = (const float*)d_in[5];
    const float* bu = (const float*)d_in[6];
    const float* Wr = (const float*)d_in[7];
    const float* br = (const float*)d_in[8];
    float* out = (float*)d_out;
    const int B = in_sizes[0] / 30;

    if (ws_size >= WS_BYTES) {
        prep_kernel<<<1, 640, 0, stream>>>(Wf, bf, Wm, bm, Wu, bu, Wr, d_ws);
        const int grid = (B + EL - 1) / EL;
        mp_mfma<<<grid, 256, 0, stream>>>(x, br, (const uint32_t*)d_ws, out, B);
    } else {
        const int grid = (B + 255) / 256;
        mp_fallback<<<grid, 256, 0, stream>>>(x, Wf, bf, Wm, bm, Wu, bu, Wr, br, out, B);
    }
}

// Round 6
// 121.198 us; speedup vs baseline: 7.2025x; 1.1487x over previous
//
#include <hip/hip_runtime.h>
#include <stdint.h>

// MessagePassing R6: elements-as-columns MFMA. Weights (transposed, bias row
// appended) are the A-operand; activations are B with col = element = lane&15.
// Every element's pipeline is column/wave-local -> ZERO __syncthreads.
// LDS is SoA planes (plane p = dword p of a column, stride 132 -> <=2-way
// conflicts, all ds offsets compile-time immediates). h stored twice (+tail)
// so stage2 AND stage3 B-reads are contiguous & branch-free; M overwrites the
// dead h-copy. Bias rides the MFMA via a constant-1 B row. R5 was VALU- and
// barrier-bound (VALU 58%, 42% idle).

#define NH 18
#define PSTR 132            // LDS plane stride, dwords
#define NPL 99              // planes: 5 slots x 18 + 9 tail
#define WS_DW 4480
#define WS_BYTES (WS_DW * 4)

typedef _Float16 half8 __attribute__((ext_vector_type(8)));
typedef float float4v __attribute__((ext_vector_type(4)));
union AB { uint32_t u[4]; half8 v; };

__device__ __forceinline__ float fast_tanh(float x) {
    float t = __builtin_amdgcn_exp2f(x * 2.8853900817779268f);
    float r = __builtin_amdgcn_rcpf(t + 1.0f);
    return __builtin_fmaf(-2.0f, r, 1.0f);
}
__device__ __forceinline__ uint32_t pkh(float a, float b) {
    union { _Float16 h[2]; uint32_t u; } z;
    z.h[0] = (_Float16)a; z.h[1] = (_Float16)b; return z.u;
}

// ---- prep: bake transposed A-frags (with bias row k=last) + Wr tables ----
// frag f at dw f*256 + lane*4 (f16x8/lane), A[m=rt*16+(lane&15)][k=ks*32+q*8+j]:
//  f0,f1: Wf^T rt0/1 (k<6 = Wf, k==6 = bf)
//  f2..5: Wm^T rt x ks (k<36 = Wm, k==36 = bm)
//  f6..9: WuFold^T rt x ks (k<18 = Wu, 18<=k<36 = Wu+Wu[+18], k==36 = bu)
// f32 tables: wrA @2560: [(n*4+r)*64+lane] = Wr[n][q*4+r]
//             wrB @3840: [(n*2+r)*64+lane] = q==0 ? Wr[n][16+r] : 0
__global__ __launch_bounds__(640) void prep_kernel(
    const float* __restrict__ Wf, const float* __restrict__ bf,
    const float* __restrict__ Wm, const float* __restrict__ bm,
    const float* __restrict__ Wu, const float* __restrict__ bu,
    const float* __restrict__ Wr, void* __restrict__ ws)
{
    uint32_t* wsd = (uint32_t*)ws;
    float* wsf = (float*)ws;
    const int tid = threadIdx.x;
    const int f = tid >> 6, lane = tid & 63;
    const int q = lane >> 4, l15 = lane & 15;
    {
        int rt, ks, which;
        if (f < 2)      { which = 0; rt = f;            ks = 0; }
        else if (f < 6) { which = 1; rt = (f - 2) >> 1; ks = (f - 2) & 1; }
        else            { which = 2; rt = (f - 6) >> 1; ks = (f - 6) & 1; }
        const int m = rt * 16 + l15;
        for (int jp = 0; jp < 4; ++jp) {
            float v[2];
            for (int h = 0; h < 2; ++h) {
                int k = ks * 32 + q * 8 + jp * 2 + h;
                float val = 0.0f;
                if (m < NH) {
                    if (which == 0) {
                        if (k < 6) val = Wf[k * NH + m];
                        else if (k == 6) val = bf[m];
                    } else if (which == 1) {
                        if (k < 36) val = Wm[k * NH + m];
                        else if (k == 36) val = bm[m];
                    } else {
                        if (k < NH) val = Wu[k * NH + m];
                        else if (k < 36) val = Wu[k * NH + m] + Wu[(k + NH) * NH + m];
                        else if (k == 36) val = bu[m];
                    }
                }
                v[h] = val;
            }
            wsd[f * 256 + lane * 4 + jp] = pkh(v[0], v[1]);
        }
    }
    for (int i = tid; i < 1280; i += 640) {
        int nr = i >> 6, ln = i & 63;
        int n = nr >> 2, r = nr & 3;
        wsf[2560 + i] = Wr[n * NH + (ln >> 4) * 4 + r];
    }
    for (int i = tid; i < 640; i += 640) {
        int nr = i >> 6, ln = i & 63;
        int n = nr >> 1, r = nr & 1;
        wsf[3840 + i] = ((ln >> 4) == 0) ? Wr[n * NH + 16 + r] : 0.0f;
    }
}

#define MFMA16(A, Bv, Cv) __builtin_amdgcn_mfma_f32_16x16x32_f16((A).v, (Bv).v, (Cv), 0, 0, 0)

__global__ __launch_bounds__(256, 3) void mp_mfma(
    const float* __restrict__ x, const float* __restrict__ br,
    const uint32_t* __restrict__ ws, float* __restrict__ out, int B)
{
    __shared__ uint32_t lds[NPL * PSTR];   // 52272 B -> 3 blocks/CU
    const int tid = threadIdx.x;
    const int lane = tid & 63, w = tid >> 6;
    const int l15 = lane & 15, q = lane >> 4;
    const float* wsf = (const float*)ws;

    AB F[10];
    #pragma unroll
    for (int f = 0; f < 10; ++f) {
        const uint32_t* p = ws + f * 256 + lane * 4;
        F[f].u[0] = p[0]; F[f].u[1] = p[1]; F[f].u[2] = p[2]; F[f].u[3] = p[3];
    }
    float wrA[5][4], wrB[5][2];
    #pragma unroll
    for (int n = 0; n < 5; ++n) {
        #pragma unroll
        for (int r = 0; r < 4; ++r) wrA[n][r] = wsf[2560 + (n * 4 + r) * 64 + lane];
        #pragma unroll
        for (int r = 0; r < 2; ++r) wrB[n][r] = wsf[3840 + (n * 2 + r) * 64 + lane];
    }
    const float brv = br[0];
    const uint32_t ONE = 0x00003C00u;          // f16 pair (1.0, 0.0): bias row
    const float4v Z = {0.f, 0.f, 0.f, 0.f};

    float racc[2];
    #pragma unroll
    for (int t = 0; t < 2; ++t) {
        const int c = (w + 4 * t) * 16 + l15;  // column = element slot (wave-private)
        const long long eg = (long long)blockIdx.x * 128 + c;

        // per-lane direct global x load (no staging barrier); f16-pack
        uint32_t xpk[5][4];
        if (eg < (long long)B) {
            const float2* xp = (const float2*)x + eg * 15;
            #pragma unroll
            for (int n = 0; n < 5; ++n) {
                float2 a = xp[n * 3], b2 = xp[n * 3 + 1], d = xp[n * 3 + 2];
                xpk[n][0] = pkh(a.x, a.y); xpk[n][1] = pkh(b2.x, b2.y);
                xpk[n][2] = pkh(d.x, d.y); xpk[n][3] = ONE;
            }
        } else {
            #pragma unroll
            for (int n = 0; n < 5; ++n) {
                xpk[n][0] = 0; xpk[n][1] = 0; xpk[n][2] = 0; xpk[n][3] = ONE;
            }
        }
        const int qc = q * 4 * PSTR + c;   // B-read addr term (plane += q*4)
        const int qw = q * 2 * PSTR + c;   // C-write addr term (plane += q*2)

        // ---- stage 1: h_n = tanh([x_n|1] @ [Wf;bf]) ----
        // h_n -> slot n first half (plane n*18) AND slot n-1 second half
        // ((n-1)*18+9; n=0 -> 81) AND (n==0) tail 90.
        #pragma unroll
        for (int n = 0; n < 5; ++n) {
            AB bx; bx.u[0] = xpk[n][0]; bx.u[1] = xpk[n][1];
                   bx.u[2] = xpk[n][2]; bx.u[3] = xpk[n][3];
            float4v C0 = MFMA16(F[0], bx, Z);
            float4v C1 = MFMA16(F[1], bx, Z);
            uint32_t p0 = pkh(fast_tanh(C0[0]), fast_tanh(C0[1]));
            uint32_t p1 = pkh(fast_tanh(C0[2]), fast_tanh(C0[3]));
            uint32_t p2 = pkh(fast_tanh(C1[0]), fast_tanh(C1[1]));
            const int P1 = n * 18;
            const int P2 = (n == 0) ? 81 : (n - 1) * 18 + 9;
            lds[P1 * PSTR + qw] = p0; lds[(P1 + 1) * PSTR + qw] = p1;
            lds[P2 * PSTR + qw] = p0; lds[(P2 + 1) * PSTR + qw] = p1;
            if (q == 0) { lds[(P1 + 8) * PSTR + c] = p2; lds[(P2 + 8) * PSTR + c] = p2; }
            if (n == 0) {
                lds[90 * PSTR + qw] = p0; lds[91 * PSTR + qw] = p1;
                if (q == 0) lds[98 * PSTR + c] = p2;
            }
        }

        // ---- stage 2: M_n = tanh([h_n|h_{n+1}|1] @ [Wm;bm]) ----
        // reads slot n (planes n*18..+17, branch-free); M_n overwrites the
        // dead h_{n+1} copy at planes n*18+9..17 (read-before-write, in order).
        #pragma unroll
        for (int n = 0; n < 5; ++n) {
            const int vb = n * 18;
            AB b0, b1;
            b0.u[0] = lds[vb * PSTR + qc];       b0.u[1] = lds[(vb + 1) * PSTR + qc];
            b0.u[2] = lds[(vb + 2) * PSTR + qc]; b0.u[3] = lds[(vb + 3) * PSTR + qc];
            b1.u[0] = lds[(vb + 16) * PSTR + c]; b1.u[1] = lds[(vb + 17) * PSTR + c];
            b1.u[2] = ONE; b1.u[3] = 0;
            float4v C0 = MFMA16(F[2], b0, Z); C0 = MFMA16(F[3], b1, C0);
            float4v C1 = MFMA16(F[4], b0, Z); C1 = MFMA16(F[5], b1, C1);
            uint32_t p0 = pkh(fast_tanh(C0[0]), fast_tanh(C0[1]));
            uint32_t p1 = pkh(fast_tanh(C0[2]), fast_tanh(C0[3]));
            uint32_t p2 = pkh(fast_tanh(C1[0]), fast_tanh(C1[1]));
            const int PM = n * 18 + 9;
            lds[PM * PSTR + qw] = p0; lds[(PM + 1) * PSTR + qw] = p1;
            if (q == 0) lds[(PM + 8) * PSTR + c] = p2;
        }

        // ---- stage 3: U2_n = tanh([M_{n-1}|h_n|1] @ [WuFold;bu]); readout ----
        // [M_{n-1}|h_n] is contiguous at planes (n-1)*18+9 (n=0 -> 81..98).
        float rc = 0.0f;
        #pragma unroll
        for (int n = 0; n < 5; ++n) {
            const int vb = (n == 0) ? 81 : (n - 1) * 18 + 9;
            AB b0, b1;
            b0.u[0] = lds[vb * PSTR + qc];       b0.u[1] = lds[(vb + 1) * PSTR + qc];
            b0.u[2] = lds[(vb + 2) * PSTR + qc]; b0.u[3] = lds[(vb + 3) * PSTR + qc];
            b1.u[0] = lds[(vb + 16) * PSTR + c]; b1.u[1] = lds[(vb + 17) * PSTR + c];
            b1.u[2] = ONE; b1.u[3] = 0;
            float4v C0 = MFMA16(F[6], b0, Z); C0 = MFMA16(F[7], b1, C0);
            float4v C1 = MFMA16(F[8], b0, Z); C1 = MFMA16(F[9], b1, C1);
            rc = __builtin_fmaf(fast_tanh(C0[0]), wrA[n][0], rc);
            rc = __builtin_fmaf(fast_tanh(C0[1]), wrA[n][1], rc);
            rc = __builtin_fmaf(fast_tanh(C0[2]), wrA[n][2], rc);
            rc = __builtin_fmaf(fast_tanh(C0[3]), wrA[n][3], rc);
            rc = __builtin_fmaf(fast_tanh(C1[0]), wrB[n][0], rc);
            rc = __builtin_fmaf(fast_tanh(C1[1]), wrB[n][1], rc);
        }
        racc[t] = rc;
    }

    // ---- readout: sum the 4 quads holding comps of each element ----
    #pragma unroll
    for (int t = 0; t < 2; ++t) {
        float s = racc[t];
        s += __shfl_xor(s, 16, 64);
        s += __shfl_xor(s, 32, 64);
        const int c = (w + 4 * t) * 16 + l15;
        const long long eg = (long long)blockIdx.x * 128 + c;
        if (q == 0 && eg < (long long)B) out[eg] = s + brv;
    }
}

// ---- Fallback (proven R1 structure, ~160 us): only if ws too small ----
__global__ __launch_bounds__(256) void mp_fallback(
    const float* __restrict__ x,
    const float* __restrict__ Wf, const float* __restrict__ bf,
    const float* __restrict__ Wm, const float* __restrict__ bm,
    const float* __restrict__ Wu, const float* __restrict__ bu,
    const float* __restrict__ Wr, const float* __restrict__ br,
    float* __restrict__ out, int B)
{
    __shared__ float sWf[6 * NH]; __shared__ float sbf[NH];
    __shared__ float sWm[36 * NH]; __shared__ float sbm[NH];
    __shared__ float sWuM[NH * NH]; __shared__ float sWuH[NH * NH];
    __shared__ float sbu[NH]; __shared__ float sWr[5 * NH];
    __shared__ float sx[256 * 30];
    const int tid = threadIdx.x;
    for (int i = tid; i < 6 * NH; i += 256) sWf[i] = Wf[i];
    for (int i = tid; i < 36 * NH; i += 256) sWm[i] = Wm[i];
    for (int i = tid; i < NH * NH; i += 256) {
        sWuM[i] = Wu[i];
        sWuH[i] = Wu[NH * NH + i] + Wu[2 * NH * NH + i];
    }
    for (int i = tid; i < 5 * NH; i += 256) sWr[i] = Wr[i];
    if (tid < NH) { sbf[tid] = bf[tid]; sbm[tid] = bm[tid]; sbu[tid] = bu[tid]; }
    const long long base = (long long)blockIdx.x * (256 * 30);
    const long long xtot = (long long)B * 30;
    for (int i = tid; i < 256 * 30; i += 256) {
        long long g = base + i;
        sx[i] = (g < xtot) ? x[g] : 0.0f;
    }
    __syncthreads();
    float h[5][NH];
    #pragma unroll
    for (int n = 0; n < 5; ++n) {
        float acc[NH];
        #pragma unroll
        for (int k = 0; k < NH; ++k) acc[k] = sbf[k];
        #pragma unroll
        for (int f = 0; f < 6; ++f) {
            float xf = sx[tid * 30 + n * 6 + f];
            #pragma unroll
            for (int k = 0; k < NH; ++k)
                acc[k] = __builtin_fmaf(xf, sWf[f * NH + k], acc[k]);
        }
        #pragma unroll
        for (int k = 0; k < NH; ++k) h[n][k] = fast_tanh(acc[k]);
    }
    float Mprev[NH];
    {
        float acc[NH];
        #pragma unroll
        for (int k = 0; k < NH; ++k) acc[k] = sbm[k];
        #pragma unroll
        for (int j = 0; j < NH; ++j) {
            float a = h[4][j], b = h[0][j];
            #pragma unroll
            for (int k = 0; k < NH; ++k)
                acc[k] = __builtin_fmaf(b, sWm[(NH + j) * NH + k],
                          __builtin_fmaf(a, sWm[j * NH + k], acc[k]));
        }
        #pragma unroll
        for (int k = 0; k < NH; ++k) Mprev[k] = fast_tanh(acc[k]);
    }
    float racc = br[0];
    #pragma unroll
    for (int n = 0; n < 5; ++n) {
        {
            float acc[NH];
            #pragma unroll
            for (int k = 0; k < NH; ++k) acc[k] = sbu[k];
            #pragma unroll
            for (int j = 0; j < NH; ++j) {
                float mval = Mprev[j], hv = h[n][j];
                #pragma unroll
                for (int k = 0; k < NH; ++k)
                    acc[k] = __builtin_fmaf(hv, sWuH[j * NH + k],
                              __builtin_fmaf(mval, sWuM[j * NH + k], acc[k]));
            }
            #pragma unroll
            for (int k = 0; k < NH; ++k)
                racc = __builtin_fmaf(fast_tanh(acc[k]), sWr[n * NH + k], racc);
        }
        if (n < 4) {
            float acc[NH];
            #pragma unroll
            for (int k = 0; k < NH; ++k) acc[k] = sbm[k];
            #pragma unroll
            for (int j = 0; j < NH; ++j) {
                float a = h[n][j], b = h[n + 1][j];
                #pragma unroll
                for (int k = 0; k < NH; ++k)
                    acc[k] = __builtin_fmaf(b, sWm[(NH + j) * NH + k],
                              __builtin_fmaf(a, sWm[j * NH + k], acc[k]));
            }
            #pragma unroll
            for (int k = 0; k < NH; ++k) Mprev[k] = fast_tanh(acc[k]);
        }
    }
    long long b = (long long)blockIdx.x * 256 + tid;
    if (b < B) out[b] = racc;
}

extern "C" void kernel_launch(void* const* d_in, const int* in_sizes, int n_in,
                              void* d_out, int out_size, void* d_ws, size_t ws_size,
                              hipStream_t stream) {
    const float* x  = (const float*)d_in[0];
    const float* Wf = (const float*)d_in[1];
    const float* bf = (const float*)d_in[2];
    const float* Wm = (const float*)d_in[3];
    const float* bm = (const float*)d_in[4];
    const float* Wu = (const float*)d_in[5];
    const float* bu = (const float*)d_in[6];
    const float* Wr = (const float*)d_in[7];
    const float* br = (const float*)d_in[8];
    float* out = (float*)d_out;
    const int B = in_sizes[0] / 30;

    if (ws_size >= WS_BYTES) {
        prep_kernel<<<1, 640, 0, stream>>>(Wf, bf, Wm, bm, Wu, bu, Wr, d_ws);
        const int grid = (B + 127) / 128;
        mp_mfma<<<grid, 256, 0, stream>>>(x, br, (const uint32_t*)d_ws, out, B);
    } else {
        const int grid = (B + 255) / 256;
        mp_fallback<<<grid, 256, 0, stream>>>(x, Wf, bf, Wm, bm, Wu, bu, Wr, br, out, B);
    }
}